// Round 18
// baseline (1290.708 us; speedup 1.0000x reference)
//
#include <hip/hip_runtime.h>
#include <math.h>

#define B 256
#define S 100
#define H 512
#define E 512
#define R 50
#define NC 5
#define H3 1536

__device__ __forceinline__ float selu_f(float x){
    return x > 0.0f ? 1.0507009873554805f * x
                    : 1.7580993408473766f * expm1f(x);   // scale*alpha
}
__device__ __forceinline__ float wred_sum(float v){
    #pragma unroll
    for (int o = 32; o > 0; o >>= 1) v += __shfl_xor(v, o);
    return v;
}
__device__ __forceinline__ float wred_maxf(float v){
    #pragma unroll
    for (int o = 32; o > 0; o >>= 1) v = fmaxf(v, __shfl_xor(v, o));
    return v;
}

// ============== 64x128 tiled f32 GEMM (16-K tile) — step fallback (ksp==4) ==============
struct GSmem {
    alignas(16) float As[16][68];
    alignas(16) float Ws[16][132];
};

__device__ __forceinline__ void gemm64(
    GSmem& sm,
    const float* __restrict__ A, int lda, int M,
    const float* __restrict__ W, int ldw,
    const float* __restrict__ bias,
    const float* __restrict__ addm, int ldadd,
    float* __restrict__ C, int ldc,
    int N, int m0, int n0, int k0beg, int k0end, int seluA)
{
    const int t  = threadIdx.x;
    const int tx = t & 15;
    const int ty = t >> 4;
    const int lm = t >> 2,  lk  = (t & 3) << 2;
    const int lw = t >> 1,  lkw = (t & 1) << 3;
    int am = m0 + lm; if (am >= M) am = M - 1;
    const float* Ap = A + (size_t)am * lda + lk;
    const int nw = n0 + lw;
    const float* Wp = W + (size_t)nw * ldw + lkw;
    const bool wok = (nw < N);
    const float4 f40 = make_float4(0.f, 0.f, 0.f, 0.f);

    float4 ar = *(const float4*)(Ap + k0beg);
    if (seluA){ ar.x = selu_f(ar.x); ar.y = selu_f(ar.y); ar.z = selu_f(ar.z); ar.w = selu_f(ar.w); }
    float4 w0 = wok ? *(const float4*)(Wp + k0beg)     : f40;
    float4 w1 = wok ? *(const float4*)(Wp + k0beg + 4) : f40;

    float acc[4][8] = {};
    for (int k0 = k0beg; k0 < k0end; k0 += 16){
        if (k0 != k0beg) __syncthreads();
        sm.As[lk+0][lm] = ar.x; sm.As[lk+1][lm] = ar.y;
        sm.As[lk+2][lm] = ar.z; sm.As[lk+3][lm] = ar.w;
        sm.Ws[lkw+0][lw] = w0.x; sm.Ws[lkw+1][lw] = w0.y;
        sm.Ws[lkw+2][lw] = w0.z; sm.Ws[lkw+3][lw] = w0.w;
        sm.Ws[lkw+4][lw] = w1.x; sm.Ws[lkw+5][lw] = w1.y;
        sm.Ws[lkw+6][lw] = w1.z; sm.Ws[lkw+7][lw] = w1.w;
        __syncthreads();
        if (k0 + 16 < k0end){
            ar = *(const float4*)(Ap + k0 + 16);
            if (seluA){ ar.x = selu_f(ar.x); ar.y = selu_f(ar.y); ar.z = selu_f(ar.z); ar.w = selu_f(ar.w); }
            w0 = wok ? *(const float4*)(Wp + k0 + 16)     : f40;
            w1 = wok ? *(const float4*)(Wp + k0 + 16 + 4) : f40;
        }
        #pragma unroll
        for (int kk = 0; kk < 16; ++kk){
            const float4 av  = *(const float4*)&sm.As[kk][ty*4];
            const float4 wv0 = *(const float4*)&sm.Ws[kk][tx*4];
            const float4 wv1 = *(const float4*)&sm.Ws[kk][tx*4 + 64];
            const float aa[4] = {av.x, av.y, av.z, av.w};
            const float bb[8] = {wv0.x, wv0.y, wv0.z, wv0.w, wv1.x, wv1.y, wv1.z, wv1.w};
            #pragma unroll
            for (int i = 0; i < 4; ++i)
                #pragma unroll
                for (int j = 0; j < 8; ++j)
                    acc[i][j] += aa[i] * bb[j];
        }
    }
    #pragma unroll
    for (int i = 0; i < 4; ++i){
        const int m = m0 + ty*4 + i;
        if (m < M){
            #pragma unroll
            for (int j = 0; j < 8; ++j){
                const int n = n0 + ((j < 4) ? (tx*4 + j) : (64 + tx*4 + j - 4));
                if (n < N){
                    float vv = acc[i][j];
                    if (bias) vv += bias[n];
                    if (addm) vv += addm[(size_t)m * ldadd + n];
                    C[(size_t)m * ldc + n] = vv;
                }
            }
        }
    }
}

// ===== 128x128 tiled f32 GEMM, 8x8/thread (R17 core): 4 b128 reads per 64 FMA =====
struct GS128 {
    alignas(16) float As[16][132];
    alignas(16) float Ws[16][132];   // 16.9 KB total
};

__device__ __forceinline__ void gemm128(
    GS128& sm,
    const float* __restrict__ A, int lda, int M,
    const float* __restrict__ W, int ldw,
    const float* __restrict__ bias,
    const float* __restrict__ addm, int ldadd,
    float* __restrict__ C, int ldc,
    int N, int m0, int n0, int K, int seluA)
{
    const int t  = threadIdx.x;
    const int tx = t & 15, ty = t >> 4;
    const int lr = t >> 1, lk = (t & 1) << 3;
    int am = m0 + lr; if (am >= M) am = M - 1;
    const float* Ap = A + (size_t)am * lda + lk;
    const int nw = n0 + lr;
    const float* Wp = W + (size_t)nw * ldw + lk;
    const bool wok = (nw < N);
    const float4 f40 = make_float4(0.f, 0.f, 0.f, 0.f);

    float4 a0 = *(const float4*)Ap;
    float4 a1 = *(const float4*)(Ap + 4);
    float4 w0 = wok ? *(const float4*)Wp       : f40;
    float4 w1 = wok ? *(const float4*)(Wp + 4) : f40;

    float acc[8][8] = {};
    for (int k0 = 0; k0 < K; k0 += 16){
        if (k0) __syncthreads();
        float4 sa0 = a0, sa1 = a1;
        if (seluA){
            sa0.x = selu_f(sa0.x); sa0.y = selu_f(sa0.y);
            sa0.z = selu_f(sa0.z); sa0.w = selu_f(sa0.w);
            sa1.x = selu_f(sa1.x); sa1.y = selu_f(sa1.y);
            sa1.z = selu_f(sa1.z); sa1.w = selu_f(sa1.w);
        }
        sm.As[lk+0][lr] = sa0.x; sm.As[lk+1][lr] = sa0.y;
        sm.As[lk+2][lr] = sa0.z; sm.As[lk+3][lr] = sa0.w;
        sm.As[lk+4][lr] = sa1.x; sm.As[lk+5][lr] = sa1.y;
        sm.As[lk+6][lr] = sa1.z; sm.As[lk+7][lr] = sa1.w;
        sm.Ws[lk+0][lr] = w0.x;  sm.Ws[lk+1][lr] = w0.y;
        sm.Ws[lk+2][lr] = w0.z;  sm.Ws[lk+3][lr] = w0.w;
        sm.Ws[lk+4][lr] = w1.x;  sm.Ws[lk+5][lr] = w1.y;
        sm.Ws[lk+6][lr] = w1.z;  sm.Ws[lk+7][lr] = w1.w;
        __syncthreads();
        if (k0 + 16 < K){
            a0 = *(const float4*)(Ap + k0 + 16);
            a1 = *(const float4*)(Ap + k0 + 20);
            w0 = wok ? *(const float4*)(Wp + k0 + 16) : f40;
            w1 = wok ? *(const float4*)(Wp + k0 + 20) : f40;
        }
        #pragma unroll
        for (int kk = 0; kk < 16; ++kk){
            const float4 av0 = *(const float4*)&sm.As[kk][ty*4];
            const float4 av1 = *(const float4*)&sm.As[kk][ty*4 + 64];
            const float4 wv0 = *(const float4*)&sm.Ws[kk][tx*4];
            const float4 wv1 = *(const float4*)&sm.Ws[kk][tx*4 + 64];
            const float aa[8] = {av0.x, av0.y, av0.z, av0.w, av1.x, av1.y, av1.z, av1.w};
            const float bb[8] = {wv0.x, wv0.y, wv0.z, wv0.w, wv1.x, wv1.y, wv1.z, wv1.w};
            #pragma unroll
            for (int i = 0; i < 8; ++i)
                #pragma unroll
                for (int j = 0; j < 8; ++j)
                    acc[i][j] += aa[i] * bb[j];
        }
    }
    #pragma unroll
    for (int i = 0; i < 8; ++i){
        const int m = m0 + ((i < 4) ? (ty*4 + i) : (64 + ty*4 + i - 4));
        if (m < M){
            #pragma unroll
            for (int j = 0; j < 8; ++j){
                const int n = n0 + ((j < 4) ? (tx*4 + j) : (64 + tx*4 + j - 4));
                if (n < N){
                    float vv = acc[i][j];
                    if (bias) vv += bias[n];
                    if (addm) vv += addm[(size_t)m * ldadd + n];
                    C[(size_t)m * ldc + n] = vv;
                }
            }
        }
    }
}

// ================= multi-job GEMM (128x128 tiles, one launch) =================
struct GemmJob {
    const float* A; int lda; long long sA; int M;
    const float* W; int ldw; long long sW;
    const float* bias; long long sBias;
    const float* addm; int ldadd; long long sAddm;
    float* C; int ldc; long long sC;
    int N, K, seluA;
    int nx, ny, base;
};
struct Jobs4 { GemmJob j[4]; };

__global__ __launch_bounds__(256) void k_mgemm(Jobs4 js)
{
    __shared__ GS128 sm;
    const int bid = blockIdx.x;
    GemmJob j;
    if      (bid >= js.j[3].base) j = js.j[3];
    else if (bid >= js.j[2].base) j = js.j[2];
    else if (bid >= js.j[1].base) j = js.j[1];
    else                          j = js.j[0];
    const int local = bid - j.base;
    const int z = local / (j.nx * j.ny);
    const int r = local % (j.nx * j.ny);
    const int y = r / j.nx, x = r % j.nx;
    gemm128(sm,
            j.A + (size_t)z * j.sA, j.lda, j.M,
            j.W + (size_t)z * j.sW, j.ldw,
            j.bias ? j.bias + (size_t)z * j.sBias : nullptr,
            j.addm ? j.addm + (size_t)z * j.sAddm : nullptr, j.ldadd,
            j.C + (size_t)z * j.sC, j.ldc,
            j.N, y * 128, x * 128, j.K, j.seluA);
}

// ==== P0: [0,8) init | [8,136) transpose | [136,392) ctx+xc | [392,396) rel_x  (396 blocks)
__global__ __launch_bounds__(256) void k_pre0(
    const float* __restrict__ sos, const float* __restrict__ dec,
    const float* __restrict__ enc, const float* __restrict__ W_attn,
    const float* __restrict__ W_comb, const float* __restrict__ b_comb,
    const float* __restrict__ rel_emb,
    float* __restrict__ emb, float* __restrict__ h0,
    float* __restrict__ WcT, float* __restrict__ xc,
    float* __restrict__ relx)
{
    __shared__ __align__(16) char smraw[sizeof(GS128)];
    const int bid = blockIdx.x, t = threadIdx.x;
    if (bid < 8){
        for (int idx = bid * 256 + t; idx < B * E; idx += 8 * 256){
            emb[idx] = sos[idx & (E - 1)];
            h0[idx]  = 0.5f * dec[idx];
        }
    } else if (bid < 136){
        float (*tile)[65] = (float(*)[65])smraw;
        const int tt = bid - 8;
        const int bx = (tt & 15) * 64;
        const int by = (tt >> 4) * 64;
        const int c4 = (t & 15) * 4, rg = t >> 4;
        for (int rr = 0; rr < 64; rr += 16){
            float4 v = *(const float4*)(W_comb + (size_t)(by + rg + rr) * (H + E) + bx + c4);
            tile[rg + rr][c4+0] = v.x; tile[rg + rr][c4+1] = v.y;
            tile[rg + rr][c4+2] = v.z; tile[rg + rr][c4+3] = v.w;
        }
        __syncthreads();
        for (int rr = 0; rr < 64; rr += 16){
            WcT[(size_t)(bx + rg + rr) * E + by + c4 + 0] = tile[c4+0][rg + rr];
            WcT[(size_t)(bx + rg + rr) * E + by + c4 + 1] = tile[c4+1][rg + rr];
            WcT[(size_t)(bx + rg + rr) * E + by + c4 + 2] = tile[c4+2][rg + rr];
            WcT[(size_t)(bx + rg + rr) * E + by + c4 + 3] = tile[c4+3][rg + rr];
        }
    } else if (bid < 392){
        float* aw   = (float*)smraw;
        float* red  = aw + 128;
        float* ctxl = red + 128;
        const int b = bid - 136;
        const int wv = t >> 6, ln = t & 63;
        const float* eb = enc + (size_t)b * S * H;
        const float* wa = W_attn + H;
        for (int s = wv; s < S; s += 4){
            const float* es = eb + (size_t)s * H;
            float a = 0.f;
            #pragma unroll
            for (int u = 0; u < H/64; ++u) a += es[ln + 64*u] * wa[ln + 64*u];
            a = wred_sum(a);
            if (ln == 0) aw[s] = a;
        }
        __syncthreads();
        float vm = (t < S) ? aw[t] : -INFINITY;
        if (t < 128) red[t] = vm;
        __syncthreads();
        for (int st = 64; st > 0; st >>= 1){
            if (t < st) red[t] = fmaxf(red[t], red[t + st]);
            __syncthreads();
        }
        const float m = red[0];
        __syncthreads();
        float e = (t < S) ? expf(aw[t] - m) : 0.f;
        if (t < 128) red[t] = e;
        __syncthreads();
        for (int st = 64; st > 0; st >>= 1){
            if (t < st) red[t] += red[t + st];
            __syncthreads();
        }
        const float sum = red[0];
        __syncthreads();
        if (t < S) aw[t] = e / sum;
        __syncthreads();
        for (int hh = t; hh < H; hh += 256){
            float a = 0.f;
            for (int s = 0; s < S; ++s) a += aw[s] * eb[(size_t)s * H + hh];
            ctxl[hh] = a;
        }
        __syncthreads();
        for (int n = wv; n < E; n += 4){
            const float* wr = W_comb + (size_t)n * (H + E) + E;
            float a = 0.f;
            #pragma unroll
            for (int u = 0; u < H/64; ++u) a += ctxl[ln + 64*u] * wr[ln + 64*u];
            a = wred_sum(a);
            if (ln == 0) xc[(size_t)b * E + n] = a + b_comb[n];
        }
    } else {
        GS128& sm = *(GS128*)smraw;
        gemm128(sm, rel_emb, E, R + 1, W_comb, H + E, nullptr, nullptr, 0,
                relx, E, E, 0, (bid - 392) * 128, E, 0);
    }
}

// ===== K64-resident step GEMM, 128x128 tile, 8x8/thread (ksp==8) =====
struct GSK128 {
    alignas(16) float As[64][132];   // 33.8 KB
    alignas(16) float Ws[64][132];   // 33.8 KB  (67.6 KB total -> 2 blocks/CU)
};

__global__ __launch_bounds__(256) void k_gru2_k128(
    const float* emb, const float* h,
    const float* Wihc, const float* Whh,
    const float* gixc, const float* bhh,
    float* gip, float* ghp, int giOn)
{
    __shared__ GSK128 sm;
    const int t = threadIdx.x;
    int xt = blockIdx.x;
    const int m0 = blockIdx.y * 128;
    const int z  = blockIdx.z;
    const int kb = z * 64;

    const float* A; int lda; const float* W; int ldw;
    const float* bias = nullptr; const float* addm = nullptr;
    float* C;
    if (giOn && xt < 12){
        A = emb; lda = E; W = Wihc; ldw = E;
        if (z == 0) addm = gixc;
        C = gip + (size_t)z * B * H3;
    } else {
        if (giOn) xt -= 12;
        A = h; lda = H; W = Whh; ldw = H;
        if (z == 0) bias = bhh;
        C = ghp + (size_t)z * B * H3;
    }
    const int n0 = xt * 128;

    // load A-tile 128x64 and W-tile 128x64 (each thread: 8+8 float4)
    {
        const int lr = t >> 1, lk = (t & 1) << 5;
        const float* Ap = A + (size_t)(m0 + lr) * lda + kb + lk;
        #pragma unroll
        for (int q = 0; q < 8; ++q){
            float4 a = *(const float4*)(Ap + 4*q);
            sm.As[lk + 4*q + 0][lr] = a.x;
            sm.As[lk + 4*q + 1][lr] = a.y;
            sm.As[lk + 4*q + 2][lr] = a.z;
            sm.As[lk + 4*q + 3][lr] = a.w;
        }
        const float* Wp = W + (size_t)(n0 + lr) * ldw + kb + lk;
        #pragma unroll
        for (int q = 0; q < 8; ++q){
            float4 w = *(const float4*)(Wp + 4*q);
            sm.Ws[lk + 4*q + 0][lr] = w.x;
            sm.Ws[lk + 4*q + 1][lr] = w.y;
            sm.Ws[lk + 4*q + 2][lr] = w.z;
            sm.Ws[lk + 4*q + 3][lr] = w.w;
        }
    }
    __syncthreads();

    const int tx = t & 15, ty = t >> 4;
    float acc[8][8] = {};
    #pragma unroll 8
    for (int kk = 0; kk < 64; ++kk){
        const float4 av0 = *(const float4*)&sm.As[kk][ty*4];
        const float4 av1 = *(const float4*)&sm.As[kk][ty*4 + 64];
        const float4 wv0 = *(const float4*)&sm.Ws[kk][tx*4];
        const float4 wv1 = *(const float4*)&sm.Ws[kk][tx*4 + 64];
        const float aa[8] = {av0.x, av0.y, av0.z, av0.w, av1.x, av1.y, av1.z, av1.w};
        const float bb[8] = {wv0.x, wv0.y, wv0.z, wv0.w, wv1.x, wv1.y, wv1.z, wv1.w};
        #pragma unroll
        for (int i = 0; i < 8; ++i)
            #pragma unroll
            for (int j = 0; j < 8; ++j)
                acc[i][j] += aa[i] * bb[j];
    }
    #pragma unroll
    for (int i = 0; i < 8; ++i){
        const int m = m0 + ((i < 4) ? (ty*4 + i) : (64 + ty*4 + i - 4));
        #pragma unroll
        for (int j = 0; j < 8; ++j){
            const int n = n0 + ((j < 4) ? (tx*4 + j) : (64 + tx*4 + j - 4));
            float vv = acc[i][j];
            if (bias) vv += bias[n];
            if (addm) vv += addm[(size_t)m * H3 + n];
            C[(size_t)m * H3 + n] = vv;
        }
    }
}

// ================= fallback per-step GEMM (ksp==4): 16-K core =================
__global__ __launch_bounds__(256) void k_gru2(
    const float* emb, const float* h,
    const float* Wihc, const float* Whh,
    const float* gixc, const float* bhh,
    float* gip, float* ghp, int giOn, int ksp)
{
    __shared__ GSmem sm;
    int xt = blockIdx.x;
    const int m0 = blockIdx.y * 64;
    const int z  = blockIdx.z;
    const int kt = H / ksp;
    const int kb = z * kt, ke = kb + kt;
    if (giOn && xt < 12){
        gemm64(sm, emb, E, B, Wihc, E, nullptr,
               (z == 0) ? gixc : nullptr, H3,
               gip + (size_t)z * B * H3, H3,
               H3, m0, xt * 128, kb, ke, 0);
    } else {
        if (giOn) xt -= 12;
        gemm64(sm, h, H, B, Whh, H,
               (z == 0) ? bhh : nullptr, nullptr, 0,
               ghp + (size_t)z * B * H3, H3,
               H3, m0, xt * 128, kb, ke, 0);
    }
}

__device__ __forceinline__ float gru_one(float gi_r, float gh_r, float gi_z, float gh_z,
                                         float gi_n, float gh_n, float hprev)
{
    const float r = 1.f / (1.f + expf(-(gi_r + gh_r)));
    const float z = 1.f / (1.f + expf(-(gi_z + gh_z)));
    const float n = tanhf(gi_n + r * gh_n);
    return (1.f - z) * n + z * hprev;
}

// ====== fused rel step ======
__global__ __launch_bounds__(256) void k_rel_fused(
    const float* __restrict__ gip, const float* __restrict__ ghp, int ksp,
    const float* __restrict__ hold,
    const float* __restrict__ Wp, const float* __restrict__ bp,
    const float* __restrict__ We, const float* __restrict__ be,
    const float* __restrict__ rel_gi_c,
    const float* __restrict__ gixc_c,
    float* __restrict__ gi_next,
    float* __restrict__ out_rel, int c,
    float* __restrict__ out_act,
    float* __restrict__ hnew_out)
{
    __shared__ alignas(16) float hn[H];
    __shared__ float logits[R + 1];
    __shared__ int   act_sh;
    const int b = blockIdx.x, t = threadIdx.x;
    const int wvi = t >> 6, ln = t & 63;
    const size_t gbase = (size_t)b * H3;
    {
        const int g = t << 1;
        float irx=0.f, iry=0.f, izx=0.f, izy=0.f, inx=0.f, iny=0.f;
        float hrx=0.f, hry=0.f, hzx=0.f, hzy=0.f, hnx=0.f, hny=0.f;
        for (int z = 0; z < ksp; ++z){
            const float* gp = gip + (size_t)z * B * H3 + gbase;
            const float* hp = ghp + (size_t)z * B * H3 + gbase;
            float2 v;
            v = *(const float2*)(gp + g);        irx += v.x; iry += v.y;
            v = *(const float2*)(gp + H + g);    izx += v.x; izy += v.y;
            v = *(const float2*)(gp + 2*H + g);  inx += v.x; iny += v.y;
            v = *(const float2*)(hp + g);        hrx += v.x; hry += v.y;
            v = *(const float2*)(hp + H + g);    hzx += v.x; hzy += v.y;
            v = *(const float2*)(hp + 2*H + g);  hnx += v.x; hny += v.y;
        }
        const float2 hprev = *(const float2*)(hold + (size_t)b * H + g);
        const float hv0 = gru_one(irx, hrx, izx, hzx, inx, hnx, hprev.x);
        const float hv1 = gru_one(iry, hry, izy, hzy, iny, hny, hprev.y);
        hn[g] = hv0; hn[g+1] = hv1;
        float2 hw; hw.x = hv0; hw.y = hv1;
        *(float2*)(hnew_out + (size_t)b * H + g) = hw;
    }
    __syncthreads();
    {
        const float4* hn4 = (const float4*)hn;
        const float4 h0 = hn4[ln*2], h1 = hn4[ln*2+1];
        for (int i = wvi; i < R + 1; i += 4){
            const float* wr = (i < R) ? Wp + (size_t)i * H : We;
            const float4* wr4 = (const float4*)wr;
            const float4 w0 = wr4[ln*2], w1 = wr4[ln*2+1];
            float a = h0.x*w0.x + h0.y*w0.y + h0.z*w0.z + h0.w*w0.w
                    + h1.x*w1.x + h1.y*w1.y + h1.z*w1.z + h1.w*w1.w;
            a = wred_sum(a);
            if (ln == 0) logits[i] = a + (i < R ? bp[i] : be[0]);
        }
    }
    __syncthreads();
    if (wvi == 0){
        const float v = (ln < R + 1) ? logits[ln] : -INFINITY;
        const float m = wred_maxf(v);
        const float p = v - m;
        const float e = (ln < R + 1) ? expf(p) : 0.f;
        const float lse = logf(wred_sum(e));
        const float q = p - lse;
        float bv = q; int bi = ln;
        #pragma unroll
        for (int o = 32; o > 0; o >>= 1){
            float ov = __shfl_xor(bv, o);
            int   oi = __shfl_xor(bi, o);
            if (ov > bv || (ov == bv && oi < bi)){ bv = ov; bi = oi; }
        }
        if (ln < R + 1)
            out_rel[(size_t)c * B * (R+1) + (size_t)b * (R+1) + ln] = q;
        if (ln == 0){
            out_act[(size_t)(3*c) * B + b] = (float)bi;
            act_sh = bi;
        }
    }
    __syncthreads();
    {
        const float4* rg4 = (const float4*)(rel_gi_c + (size_t)act_sh * H3);
        const float4* gx4 = (const float4*)(gixc_c + gbase);
        float4* go4 = (float4*)(gi_next + gbase);
        for (int u = t; u < H3/4; u += 256){
            float4 a = rg4[u], bq = gx4[u];
            a.x += bq.x; a.y += bq.y; a.z += bq.z; a.w += bq.w;
            go4[u] = a;
        }
    }
}

// == fused copy step ==
__global__ __launch_bounds__(256) void k_copy_fused(
    const float* __restrict__ gip, const float* __restrict__ ghp,
    int gi_full, int ksp,
    const float* __restrict__ v,
    const float* __restrict__ hold,
    const float* __restrict__ W_fuse, const float* __restrict__ b_fuse,
    const float* __restrict__ W_copy, const float* __restrict__ b_copy,
    const float* __restrict__ We, const float* __restrict__ be,
    const int* __restrict__ sentence, const float* __restrict__ word_emb,
    float* __restrict__ out_copy, int slot,
    float* __restrict__ emb, float* __restrict__ out_act, int aslot,
    float* __restrict__ hnew_out, const float* __restrict__ dec, int cell_end)
{
    __shared__ alignas(16) float hn[H];
    __shared__ alignas(16) float shl[H];
    __shared__ float u_lds[100];
    __shared__ float wc_lds[100];
    __shared__ float sco[101];
    __shared__ int   act_sh;
    const int b = blockIdx.x, t = threadIdx.x;
    const int wvi = t >> 6, ln = t & 63;
    const size_t gbase = (size_t)b * H3;
    {
        const int g = t << 1;
        float irx, iry, izx, izy, inx, iny;
        if (gi_full){
            float2 v2;
            v2 = *(const float2*)(gip + gbase + g);        irx = v2.x; iry = v2.y;
            v2 = *(const float2*)(gip + gbase + H + g);    izx = v2.x; izy = v2.y;
            v2 = *(const float2*)(gip + gbase + 2*H + g);  inx = v2.x; iny = v2.y;
        } else {
            irx = iry = izx = izy = inx = iny = 0.f;
            for (int z = 0; z < ksp; ++z){
                const float* gp = gip + (size_t)z * B * H3 + gbase;
                float2 v2;
                v2 = *(const float2*)(gp + g);        irx += v2.x; iry += v2.y;
                v2 = *(const float2*)(gp + H + g);    izx += v2.x; izy += v2.y;
                v2 = *(const float2*)(gp + 2*H + g);  inx += v2.x; iny += v2.y;
            }
        }
        float hrx=0.f, hry=0.f, hzx=0.f, hzy=0.f, hnx=0.f, hny=0.f;
        for (int z = 0; z < ksp; ++z){
            const float* hp = ghp + (size_t)z * B * H3 + gbase;
            float2 v2;
            v2 = *(const float2*)(hp + g);        hrx += v2.x; hry += v2.y;
            v2 = *(const float2*)(hp + H + g);    hzx += v2.x; hzy += v2.y;
            v2 = *(const float2*)(hp + 2*H + g);  hnx += v2.x; hny += v2.y;
        }
        const float2 hprev = *(const float2*)(hold + (size_t)b * H + g);
        const float hv0 = gru_one(irx, hrx, izx, hzx, inx, hnx, hprev.x);
        const float hv1 = gru_one(iry, hry, izy, hzy, iny, hny, hprev.y);
        hn[g] = hv0; hn[g+1] = hv1;
        shl[g] = selu_f(hv0); shl[g+1] = selu_f(hv1);
        float2 hw;
        if (cell_end){
            const float2 d2 = *(const float2*)(dec + (size_t)b * H + g);
            hw.x = 0.5f * (d2.x + hv0); hw.y = 0.5f * (d2.y + hv1);
        } else { hw.x = hv0; hw.y = hv1; }
        *(float2*)(hnew_out + (size_t)b * H + g) = hw;
    }
    if (t < 100) wc_lds[t] = W_copy[t];
    __syncthreads();
    {
        const float4* sh4 = (const float4*)shl;
        const float4 s0 = sh4[ln*2], s1 = sh4[ln*2+1];
        for (int n = wvi; n < 100; n += 4){
            const float4* wr4 = (const float4*)(W_fuse + (size_t)n * (2*H));
            const float4 w0 = wr4[ln*2], w1 = wr4[ln*2+1];
            float a = s0.x*w0.x + s0.y*w0.y + s0.z*w0.z + s0.w*w0.w
                    + s1.x*w1.x + s1.y*w1.y + s1.z*w1.z + s1.w*w1.w;
            a = wred_sum(a);
            if (ln == 0) u_lds[n] = a + b_fuse[n];
        }
        if (wvi == 3){
            const float4* hn4 = (const float4*)hn;
            const float4 h0 = hn4[ln*2], h1 = hn4[ln*2+1];
            const float4* we4 = (const float4*)We;
            const float4 w0 = we4[ln*2], w1 = we4[ln*2+1];
            float a = h0.x*w0.x + h0.y*w0.y + h0.z*w0.z + h0.w*w0.w
                    + h1.x*w1.x + h1.y*w1.y + h1.z*w1.z + h1.w*w1.w;
            a = wred_sum(a);
            if (ln == 0) sco[100] = a + be[0];
        }
    }
    __syncthreads();
    const float bc = b_copy[0];
    for (int s = wvi; s < S; s += 4){
        const float* vb = v + ((size_t)b * S + s) * 100;
        float a = selu_f(u_lds[ln] + vb[ln]) * wc_lds[ln];
        if (ln + 64 < 100) a += selu_f(u_lds[ln + 64] + vb[ln + 64]) * wc_lds[ln + 64];
        a = wred_sum(a);
        if (ln == 0) sco[s] = a + bc;
    }
    __syncthreads();
    if (wvi == 0){
        const float v1 = sco[ln];
        const int i2 = ln + 64;
        const float v2 = (i2 <= S) ? sco[i2] : -INFINITY;
        const float m = wred_maxf(fmaxf(v1, v2));
        const float p1 = v1 - m, p2 = v2 - m;
        float e = expf(p1) + ((i2 <= S) ? expf(p2) : 0.f);
        const float lse = logf(wred_sum(e));
        const float q1 = p1 - lse, q2 = p2 - lse;
        float bv; int bi;
        if (q2 > q1){ bv = q2; bi = i2; } else { bv = q1; bi = ln; }
        #pragma unroll
        for (int o = 32; o > 0; o >>= 1){
            float ov = __shfl_xor(bv, o);
            int   oi = __shfl_xor(bi, o);
            if (ov > bv || (ov == bv && oi < bi)){ bv = ov; bi = oi; }
        }
        const size_t obase = (size_t)slot * B * (S+1) + (size_t)b * (S+1);
        out_copy[obase + ln] = q1;
        if (i2 <= S) out_copy[obase + i2] = q2;
        if (ln == 0){
            out_act[(size_t)aslot * B + b] = (float)bi;
            act_sh = bi;
        }
    }
    __syncthreads();
    const int act = act_sh;
    const int wd = sentence[b * S + (act < S ? act : S - 1)];
    const float2* wr2 = (const float2*)(word_emb + (size_t)wd * E);
    ((float2*)(emb + (size_t)b * E))[t] = wr2[t];
}

extern "C" void kernel_launch(void* const* d_in, const int* in_sizes, int n_in,
                              void* d_out, int out_size, void* d_ws, size_t ws_size,
                              hipStream_t stream)
{
    (void)in_sizes; (void)n_in; (void)out_size;
    const int*   sentence = (const int*)  d_in[0];
    const float* dec      = (const float*)d_in[1];
    const float* enc      = (const float*)d_in[2];
    const float* word_emb = (const float*)d_in[3];
    const float* rel_emb  = (const float*)d_in[4];
    const float* sos      = (const float*)d_in[5];
    const float* W_comb   = (const float*)d_in[6];
    const float* b_comb   = (const float*)d_in[7];
    const float* W_attn   = (const float*)d_in[8];
    // d_in[9] = b_attn (cancels in softmax)
    const float* W_ih     = (const float*)d_in[10];
    const float* W_hh     = (const float*)d_in[11];
    const float* b_ih     = (const float*)d_in[12];
    const float* b_hh     = (const float*)d_in[13];
    const float* W_eos    = (const float*)d_in[14];
    const float* b_eos    = (const float*)d_in[15];
    const float* W_pred   = (const float*)d_in[16];
    const float* b_pred   = (const float*)d_in[17];
    const float* W_fuse   = (const float*)d_in[18];
    const float* b_fuse   = (const float*)d_in[19];
    const float* W_copy   = (const float*)d_in[20];
    const float* b_copy   = (const float*)d_in[21];

    float* out       = (float*)d_out;
    float* out_rel   = out;
    float* out_copy  = out + (size_t)NC * B * (R + 1);
    float* out_act   = out_copy + (size_t)2 * NC * B * (S + 1);

    float* p = (float*)d_ws;
    float* v_buf  = p; p += (size_t)B * S * 100;
    float* Wihc   = p; p += (size_t)NC * H3 * E;
    float* gixc   = p; p += (size_t)NC * B * H3;
    float* rel_gi = p; p += (size_t)NC * 64 * H3;
    float* WcT    = p; p += (size_t)(H + E) * E;
    float* relx   = p; p += (size_t)64 * E;
    float* xc     = p; p += B * E;
    float* emb    = p; p += B * E;
    float* hb0    = p; p += B * H;
    float* hb1    = p; p += B * H;
    const size_t fixed_floats = (size_t)(p - (float*)d_ws);
    int ksp = 8;
    if ((fixed_floats + (size_t)2 * 8 * B * H3) * 4 > ws_size) ksp = 4;
    float* gip = p; p += (size_t)ksp * B * H3;
    float* ghp = p; p += (size_t)ksp * B * H3;
    float* hb[2] = { hb0, hb1 };

    // ---- P0 (396 blocks): init + transpose + ctx->xc + rel_x ----
    k_pre0<<<396, 256, 0, stream>>>(sos, dec, enc, W_attn, W_comb, b_comb, rel_emb,
                                    emb, hb0, WcT, xc, relx);

    // ---- P1 mega multi-GEMM {Wihc, gixc, rel_gi, v_buf}: 620 blocks ----
    Jobs4 js;
    js.j[0] = { W_ih, E, (long long)H3 * E, H3,
                WcT, E, 0, nullptr, 0, nullptr, 0, 0,
                Wihc, E, (long long)H3 * E, E, E, 0, 4, 12, 0 };
    js.j[1] = { xc, E, 0, B,
                W_ih, E, (long long)H3 * E, b_ih, H3, nullptr, 0, 0,
                gixc, H3, (long long)B * H3, H3, E, 0, 12, 2, 240 };
    js.j[2] = { relx, E, 0, R + 1,
                W_ih, E, (long long)H3 * E, nullptr, 0, nullptr, 0, 0,
                rel_gi, H3, (long long)64 * H3, H3, E, 0, 12, 1, 360 };
    js.j[3] = { enc, H, 0, B * S,
                W_fuse + H, 2 * H, 0, nullptr, 0, nullptr, 0, 0,
                v_buf, 100, 0, 100, H, 1, 1, 200, 420 };
    k_mgemm<<<620, 256, 0, stream>>>(js);

    int cur = 0;
    for (int c = 0; c < NC; ++c){
        const float* Wihc_c = Wihc + (size_t)c * H3 * E;
        const float* Whh_c  = W_hh + (size_t)c * H3 * H;
        const float* gixc_c = gixc + (size_t)c * B * H3;
        const float* bhh_c  = b_hh + (size_t)c * H3;
        for (int t3 = 0; t3 < 3; ++t3){
            const int giOn = (t3 != 1);
            if (ksp == 8){
                k_gru2_k128<<<dim3(giOn ? 24 : 12, 2, 8), 256, 0, stream>>>(
                    emb, hb[cur], Wihc_c, Whh_c, gixc_c, bhh_c,
                    gip, ghp, giOn);
            } else {
                k_gru2<<<dim3(giOn ? 24 : 12, 4, ksp), 256, 0, stream>>>(
                    emb, hb[cur], Wihc_c, Whh_c, gixc_c, bhh_c,
                    gip, ghp, giOn, ksp);
            }
            if (t3 == 0){
                k_rel_fused<<<B, 256, 0, stream>>>(
                    gip, ghp, ksp, hb[cur], W_pred, b_pred, W_eos, b_eos,
                    rel_gi + (size_t)c * 64 * H3, gixc_c, gip,
                    out_rel, c, out_act, hb[cur^1]);
            } else {
                k_copy_fused<<<B, 256, 0, stream>>>(
                    gip, ghp, (t3 == 1) ? 1 : 0, ksp, v_buf, hb[cur],
                    W_fuse, b_fuse, W_copy, b_copy, W_eos, b_eos,
                    sentence, word_emb,
                    out_copy, 2*c + (t3-1), emb, out_act, 3*c + t3,
                    hb[cur^1], dec, (t3 == 2) ? 1 : 0);
            }
            cur ^= 1;
        }
    }
}

// Round 19
// 872.846 us; speedup vs baseline: 1.4787x; 1.4787x over previous
//
#include <hip/hip_runtime.h>
#include <math.h>

#define B 256
#define S 100
#define H 512
#define E 512
#define R 50
#define NC 5
#define H3 1536

__device__ __forceinline__ float selu_f(float x){
    return x > 0.0f ? 1.0507009873554805f * x
                    : 1.7580993408473766f * expm1f(x);   // scale*alpha
}
__device__ __forceinline__ float wred_sum(float v){
    #pragma unroll
    for (int o = 32; o > 0; o >>= 1) v += __shfl_xor(v, o);
    return v;
}
__device__ __forceinline__ float wred_maxf(float v){
    #pragma unroll
    for (int o = 32; o > 0; o >>= 1) v = fmaxf(v, __shfl_xor(v, o));
    return v;
}

// ============== 64x128 tiled f32 GEMM (16-K tile) — step fallback (ksp==4) ==============
struct GSmem {
    alignas(16) float As[16][68];
    alignas(16) float Ws[16][132];
};

__device__ __forceinline__ void gemm64(
    GSmem& sm,
    const float* __restrict__ A, int lda, int M,
    const float* __restrict__ W, int ldw,
    const float* __restrict__ bias,
    const float* __restrict__ addm, int ldadd,
    float* __restrict__ C, int ldc,
    int N, int m0, int n0, int k0beg, int k0end, int seluA)
{
    const int t  = threadIdx.x;
    const int tx = t & 15;
    const int ty = t >> 4;
    const int lm = t >> 2,  lk  = (t & 3) << 2;
    const int lw = t >> 1,  lkw = (t & 1) << 3;
    int am = m0 + lm; if (am >= M) am = M - 1;
    const float* Ap = A + (size_t)am * lda + lk;
    const int nw = n0 + lw;
    const float* Wp = W + (size_t)nw * ldw + lkw;
    const bool wok = (nw < N);
    const float4 f40 = make_float4(0.f, 0.f, 0.f, 0.f);

    float4 ar = *(const float4*)(Ap + k0beg);
    if (seluA){ ar.x = selu_f(ar.x); ar.y = selu_f(ar.y); ar.z = selu_f(ar.z); ar.w = selu_f(ar.w); }
    float4 w0 = wok ? *(const float4*)(Wp + k0beg)     : f40;
    float4 w1 = wok ? *(const float4*)(Wp + k0beg + 4) : f40;

    float acc[4][8] = {};
    for (int k0 = k0beg; k0 < k0end; k0 += 16){
        if (k0 != k0beg) __syncthreads();
        sm.As[lk+0][lm] = ar.x; sm.As[lk+1][lm] = ar.y;
        sm.As[lk+2][lm] = ar.z; sm.As[lk+3][lm] = ar.w;
        sm.Ws[lkw+0][lw] = w0.x; sm.Ws[lkw+1][lw] = w0.y;
        sm.Ws[lkw+2][lw] = w0.z; sm.Ws[lkw+3][lw] = w0.w;
        sm.Ws[lkw+4][lw] = w1.x; sm.Ws[lkw+5][lw] = w1.y;
        sm.Ws[lkw+6][lw] = w1.z; sm.Ws[lkw+7][lw] = w1.w;
        __syncthreads();
        if (k0 + 16 < k0end){
            ar = *(const float4*)(Ap + k0 + 16);
            if (seluA){ ar.x = selu_f(ar.x); ar.y = selu_f(ar.y); ar.z = selu_f(ar.z); ar.w = selu_f(ar.w); }
            w0 = wok ? *(const float4*)(Wp + k0 + 16)     : f40;
            w1 = wok ? *(const float4*)(Wp + k0 + 16 + 4) : f40;
        }
        #pragma unroll
        for (int kk = 0; kk < 16; ++kk){
            const float4 av  = *(const float4*)&sm.As[kk][ty*4];
            const float4 wv0 = *(const float4*)&sm.Ws[kk][tx*4];
            const float4 wv1 = *(const float4*)&sm.Ws[kk][tx*4 + 64];
            const float aa[4] = {av.x, av.y, av.z, av.w};
            const float bb[8] = {wv0.x, wv0.y, wv0.z, wv0.w, wv1.x, wv1.y, wv1.z, wv1.w};
            #pragma unroll
            for (int i = 0; i < 4; ++i)
                #pragma unroll
                for (int j = 0; j < 8; ++j)
                    acc[i][j] += aa[i] * bb[j];
        }
    }
    #pragma unroll
    for (int i = 0; i < 4; ++i){
        const int m = m0 + ty*4 + i;
        if (m < M){
            #pragma unroll
            for (int j = 0; j < 8; ++j){
                const int n = n0 + ((j < 4) ? (tx*4 + j) : (64 + tx*4 + j - 4));
                if (n < N){
                    float vv = acc[i][j];
                    if (bias) vv += bias[n];
                    if (addm) vv += addm[(size_t)m * ldadd + n];
                    C[(size_t)m * ldc + n] = vv;
                }
            }
        }
    }
}

// ===== 128x128 tiled f32 GEMM, 8x8/thread (R17 core) =====
struct GS128 {
    alignas(16) float As[16][132];
    alignas(16) float Ws[16][132];   // 16.9 KB total
};

__device__ __forceinline__ void gemm128(
    GS128& sm,
    const float* __restrict__ A, int lda, int M,
    const float* __restrict__ W, int ldw,
    const float* __restrict__ bias,
    const float* __restrict__ addm, int ldadd,
    float* __restrict__ C, int ldc,
    int N, int m0, int n0, int K, int seluA)
{
    const int t  = threadIdx.x;
    const int tx = t & 15, ty = t >> 4;
    const int lr = t >> 1, lk = (t & 1) << 3;
    int am = m0 + lr; if (am >= M) am = M - 1;
    const float* Ap = A + (size_t)am * lda + lk;
    const int nw = n0 + lr;
    const float* Wp = W + (size_t)nw * ldw + lk;
    const bool wok = (nw < N);
    const float4 f40 = make_float4(0.f, 0.f, 0.f, 0.f);

    float4 a0 = *(const float4*)Ap;
    float4 a1 = *(const float4*)(Ap + 4);
    float4 w0 = wok ? *(const float4*)Wp       : f40;
    float4 w1 = wok ? *(const float4*)(Wp + 4) : f40;

    float acc[8][8] = {};
    for (int k0 = 0; k0 < K; k0 += 16){
        if (k0) __syncthreads();
        float4 sa0 = a0, sa1 = a1;
        if (seluA){
            sa0.x = selu_f(sa0.x); sa0.y = selu_f(sa0.y);
            sa0.z = selu_f(sa0.z); sa0.w = selu_f(sa0.w);
            sa1.x = selu_f(sa1.x); sa1.y = selu_f(sa1.y);
            sa1.z = selu_f(sa1.z); sa1.w = selu_f(sa1.w);
        }
        sm.As[lk+0][lr] = sa0.x; sm.As[lk+1][lr] = sa0.y;
        sm.As[lk+2][lr] = sa0.z; sm.As[lk+3][lr] = sa0.w;
        sm.As[lk+4][lr] = sa1.x; sm.As[lk+5][lr] = sa1.y;
        sm.As[lk+6][lr] = sa1.z; sm.As[lk+7][lr] = sa1.w;
        sm.Ws[lk+0][lr] = w0.x;  sm.Ws[lk+1][lr] = w0.y;
        sm.Ws[lk+2][lr] = w0.z;  sm.Ws[lk+3][lr] = w0.w;
        sm.Ws[lk+4][lr] = w1.x;  sm.Ws[lk+5][lr] = w1.y;
        sm.Ws[lk+6][lr] = w1.z;  sm.Ws[lk+7][lr] = w1.w;
        __syncthreads();
        if (k0 + 16 < K){
            a0 = *(const float4*)(Ap + k0 + 16);
            a1 = *(const float4*)(Ap + k0 + 20);
            w0 = wok ? *(const float4*)(Wp + k0 + 16) : f40;
            w1 = wok ? *(const float4*)(Wp + k0 + 20) : f40;
        }
        #pragma unroll
        for (int kk = 0; kk < 16; ++kk){
            const float4 av0 = *(const float4*)&sm.As[kk][ty*4];
            const float4 av1 = *(const float4*)&sm.As[kk][ty*4 + 64];
            const float4 wv0 = *(const float4*)&sm.Ws[kk][tx*4];
            const float4 wv1 = *(const float4*)&sm.Ws[kk][tx*4 + 64];
            const float aa[8] = {av0.x, av0.y, av0.z, av0.w, av1.x, av1.y, av1.z, av1.w};
            const float bb[8] = {wv0.x, wv0.y, wv0.z, wv0.w, wv1.x, wv1.y, wv1.z, wv1.w};
            #pragma unroll
            for (int i = 0; i < 8; ++i)
                #pragma unroll
                for (int j = 0; j < 8; ++j)
                    acc[i][j] += aa[i] * bb[j];
        }
    }
    #pragma unroll
    for (int i = 0; i < 8; ++i){
        const int m = m0 + ((i < 4) ? (ty*4 + i) : (64 + ty*4 + i - 4));
        if (m < M){
            #pragma unroll
            for (int j = 0; j < 8; ++j){
                const int n = n0 + ((j < 4) ? (tx*4 + j) : (64 + tx*4 + j - 4));
                if (n < N){
                    float vv = acc[i][j];
                    if (bias) vv += bias[n];
                    if (addm) vv += addm[(size_t)m * ldadd + n];
                    C[(size_t)m * ldc + n] = vv;
                }
            }
        }
    }
}

// ================= multi-job GEMM (128x128 tiles, one launch) =================
struct GemmJob {
    const float* A; int lda; long long sA; int M;
    const float* W; int ldw; long long sW;
    const float* bias; long long sBias;
    const float* addm; int ldadd; long long sAddm;
    float* C; int ldc; long long sC;
    int N, K, seluA;
    int nx, ny, base;
};
struct Jobs4 { GemmJob j[4]; };

__global__ __launch_bounds__(256) void k_mgemm(Jobs4 js)
{
    __shared__ GS128 sm;
    const int bid = blockIdx.x;
    GemmJob j;
    if      (bid >= js.j[3].base) j = js.j[3];
    else if (bid >= js.j[2].base) j = js.j[2];
    else if (bid >= js.j[1].base) j = js.j[1];
    else                          j = js.j[0];
    const int local = bid - j.base;
    const int z = local / (j.nx * j.ny);
    const int r = local % (j.nx * j.ny);
    const int y = r / j.nx, x = r % j.nx;
    gemm128(sm,
            j.A + (size_t)z * j.sA, j.lda, j.M,
            j.W + (size_t)z * j.sW, j.ldw,
            j.bias ? j.bias + (size_t)z * j.sBias : nullptr,
            j.addm ? j.addm + (size_t)z * j.sAddm : nullptr, j.ldadd,
            j.C + (size_t)z * j.sC, j.ldc,
            j.N, y * 128, x * 128, j.K, j.seluA);
}

// ==== P0 (R17): [0,8) init | [8,136) transpose | [136,392) ctx+xc | [392,396) rel_x | [396,596) v_buf
__global__ __launch_bounds__(256) void k_pre0(
    const float* __restrict__ sos, const float* __restrict__ dec,
    const float* __restrict__ enc, const float* __restrict__ W_attn,
    const float* __restrict__ W_comb, const float* __restrict__ b_comb,
    const float* __restrict__ rel_emb, const float* __restrict__ W_fuse,
    float* __restrict__ emb, float* __restrict__ h0,
    float* __restrict__ WcT, float* __restrict__ xc,
    float* __restrict__ relx, float* __restrict__ v_buf)
{
    __shared__ __align__(16) char smraw[sizeof(GS128)];
    const int bid = blockIdx.x, t = threadIdx.x;
    if (bid < 8){
        for (int idx = bid * 256 + t; idx < B * E; idx += 8 * 256){
            emb[idx] = sos[idx & (E - 1)];
            h0[idx]  = 0.5f * dec[idx];
        }
    } else if (bid < 136){
        float (*tile)[65] = (float(*)[65])smraw;
        const int tt = bid - 8;
        const int bx = (tt & 15) * 64;
        const int by = (tt >> 4) * 64;
        const int c4 = (t & 15) * 4, rg = t >> 4;
        for (int rr = 0; rr < 64; rr += 16){
            float4 v = *(const float4*)(W_comb + (size_t)(by + rg + rr) * (H + E) + bx + c4);
            tile[rg + rr][c4+0] = v.x; tile[rg + rr][c4+1] = v.y;
            tile[rg + rr][c4+2] = v.z; tile[rg + rr][c4+3] = v.w;
        }
        __syncthreads();
        for (int rr = 0; rr < 64; rr += 16){
            WcT[(size_t)(bx + rg + rr) * E + by + c4 + 0] = tile[c4+0][rg + rr];
            WcT[(size_t)(bx + rg + rr) * E + by + c4 + 1] = tile[c4+1][rg + rr];
            WcT[(size_t)(bx + rg + rr) * E + by + c4 + 2] = tile[c4+2][rg + rr];
            WcT[(size_t)(bx + rg + rr) * E + by + c4 + 3] = tile[c4+3][rg + rr];
        }
    } else if (bid < 392){
        float* aw   = (float*)smraw;
        float* red  = aw + 128;
        float* ctxl = red + 128;
        const int b = bid - 136;
        const int wv = t >> 6, ln = t & 63;
        const float* eb = enc + (size_t)b * S * H;
        const float* wa = W_attn + H;
        for (int s = wv; s < S; s += 4){
            const float* es = eb + (size_t)s * H;
            float a = 0.f;
            #pragma unroll
            for (int u = 0; u < H/64; ++u) a += es[ln + 64*u] * wa[ln + 64*u];
            a = wred_sum(a);
            if (ln == 0) aw[s] = a;
        }
        __syncthreads();
        float vm = (t < S) ? aw[t] : -INFINITY;
        if (t < 128) red[t] = vm;
        __syncthreads();
        for (int st = 64; st > 0; st >>= 1){
            if (t < st) red[t] = fmaxf(red[t], red[t + st]);
            __syncthreads();
        }
        const float m = red[0];
        __syncthreads();
        float e = (t < S) ? expf(aw[t] - m) : 0.f;
        if (t < 128) red[t] = e;
        __syncthreads();
        for (int st = 64; st > 0; st >>= 1){
            if (t < st) red[t] += red[t + st];
            __syncthreads();
        }
        const float sum = red[0];
        __syncthreads();
        if (t < S) aw[t] = e / sum;
        __syncthreads();
        for (int hh = t; hh < H; hh += 256){
            float a = 0.f;
            for (int s = 0; s < S; ++s) a += aw[s] * eb[(size_t)s * H + hh];
            ctxl[hh] = a;
        }
        __syncthreads();
        for (int n = wv; n < E; n += 4){
            const float* wr = W_comb + (size_t)n * (H + E) + E;
            float a = 0.f;
            #pragma unroll
            for (int u = 0; u < H/64; ++u) a += ctxl[ln + 64*u] * wr[ln + 64*u];
            a = wred_sum(a);
            if (ln == 0) xc[(size_t)b * E + n] = a + b_comb[n];
        }
    } else if (bid < 396){
        GS128& sm = *(GS128*)smraw;
        gemm128(sm, rel_emb, E, R + 1, W_comb, H + E, nullptr, nullptr, 0,
                relx, E, E, 0, (bid - 392) * 128, E, 0);
    } else {
        GS128& sm = *(GS128*)smraw;
        gemm128(sm, enc, H, B * S, W_fuse + H, 2 * H, nullptr, nullptr, 0,
                v_buf, 100, 100, (bid - 396) * 128, 0, H, 1);
    }
}

// ============ K64-resident step GEMM (R15/R17, ksp==8): 3 blocks/CU ============
struct GSmemK64 {
    alignas(16) float As[64][68];
    alignas(16) float Ws[64][132];
};

__global__ __launch_bounds__(256) void k_gru2_k64(
    const float* emb, const float* h,
    const float* Wihc, const float* Whh,
    const float* gixc, const float* bhh,
    float* gip, float* ghp, int giOn)
{
    __shared__ GSmemK64 sm;
    const int t = threadIdx.x;
    int xt = blockIdx.x;
    const int m0 = blockIdx.y * 64;
    const int z  = blockIdx.z;
    const int kb = z * 64;

    const float* A; int lda; const float* W; int ldw;
    const float* bias = nullptr; const float* addm = nullptr;
    float* C;
    if (giOn && xt < 12){
        A = emb; lda = E; W = Wihc; ldw = E;
        if (z == 0) addm = gixc;
        C = gip + (size_t)z * B * H3;
    } else {
        if (giOn) xt -= 12;
        A = h; lda = H; W = Whh; ldw = H;
        if (z == 0) bias = bhh;
        C = ghp + (size_t)z * B * H3;
    }
    const int n0 = xt * 128;

    {
        const int lm = t >> 2, ks = (t & 3) << 4;
        const float* Ap = A + (size_t)(m0 + lm) * lda + kb + ks;
        #pragma unroll
        for (int q = 0; q < 4; ++q){
            float4 a = *(const float4*)(Ap + 4*q);
            sm.As[ks + 4*q + 0][lm] = a.x;
            sm.As[ks + 4*q + 1][lm] = a.y;
            sm.As[ks + 4*q + 2][lm] = a.z;
            sm.As[ks + 4*q + 3][lm] = a.w;
        }
    }
    {
        const int lw = t >> 1, ks2 = (t & 1) << 5;
        const float* Wp = W + (size_t)(n0 + lw) * ldw + kb + ks2;
        #pragma unroll
        for (int q = 0; q < 8; ++q){
            float4 w = *(const float4*)(Wp + 4*q);
            sm.Ws[ks2 + 4*q + 0][lw] = w.x;
            sm.Ws[ks2 + 4*q + 1][lw] = w.y;
            sm.Ws[ks2 + 4*q + 2][lw] = w.z;
            sm.Ws[ks2 + 4*q + 3][lw] = w.w;
        }
    }
    __syncthreads();

    const int tx = t & 15, ty = t >> 4;
    float acc[4][8] = {};
    #pragma unroll 16
    for (int kk = 0; kk < 64; ++kk){
        const float4 av  = *(const float4*)&sm.As[kk][ty*4];
        const float4 wv0 = *(const float4*)&sm.Ws[kk][tx*4];
        const float4 wv1 = *(const float4*)&sm.Ws[kk][tx*4 + 64];
        const float aa[4] = {av.x, av.y, av.z, av.w};
        const float bb[8] = {wv0.x, wv0.y, wv0.z, wv0.w, wv1.x, wv1.y, wv1.z, wv1.w};
        #pragma unroll
        for (int i = 0; i < 4; ++i)
            #pragma unroll
            for (int j = 0; j < 8; ++j)
                acc[i][j] += aa[i] * bb[j];
    }
    #pragma unroll
    for (int i = 0; i < 4; ++i){
        const int m = m0 + ty*4 + i;
        #pragma unroll
        for (int j = 0; j < 8; ++j){
            const int n = n0 + ((j < 4) ? (tx*4 + j) : (64 + tx*4 + j - 4));
            float vv = acc[i][j];
            if (bias) vv += bias[n];
            if (addm) vv += addm[(size_t)m * H3 + n];
            C[(size_t)m * H3 + n] = vv;
        }
    }
}

// ================= fallback per-step GEMM (ksp==4) =================
__global__ __launch_bounds__(256) void k_gru2(
    const float* emb, const float* h,
    const float* Wihc, const float* Whh,
    const float* gixc, const float* bhh,
    float* gip, float* ghp, int giOn, int ksp)
{
    __shared__ GSmem sm;
    int xt = blockIdx.x;
    const int m0 = blockIdx.y * 64;
    const int z  = blockIdx.z;
    const int kt = H / ksp;
    const int kb = z * kt, ke = kb + kt;
    if (giOn && xt < 12){
        gemm64(sm, emb, E, B, Wihc, E, nullptr,
               (z == 0) ? gixc : nullptr, H3,
               gip + (size_t)z * B * H3, H3,
               H3, m0, xt * 128, kb, ke, 0);
    } else {
        if (giOn) xt -= 12;
        gemm64(sm, h, H, B, Whh, H,
               (z == 0) ? bhh : nullptr, nullptr, 0,
               ghp + (size_t)z * B * H3, H3,
               H3, m0, xt * 128, kb, ke, 0);
    }
}

__device__ __forceinline__ float gru_one(float gi_r, float gh_r, float gi_z, float gh_z,
                                         float gi_n, float gh_n, float hprev)
{
    const float r = 1.f / (1.f + expf(-(gi_r + gh_r)));
    const float z = 1.f / (1.f + expf(-(gi_z + gh_z)));
    const float n = tanhf(gi_n + r * gh_n);
    return (1.f - z) * n + z * hprev;
}

// ====== fused rel step — 512 threads (2 waves/SIMD for latency hiding) ======
__global__ __launch_bounds__(512) void k_rel_fused(
    const float* __restrict__ gip, const float* __restrict__ ghp, int ksp,
    const float* __restrict__ hold,
    const float* __restrict__ Wp, const float* __restrict__ bp,
    const float* __restrict__ We, const float* __restrict__ be,
    const float* __restrict__ rel_gi_c,
    const float* __restrict__ gixc_c,
    float* __restrict__ gi_next,
    float* __restrict__ out_rel, int c,
    float* __restrict__ out_act,
    float* __restrict__ hnew_out)
{
    __shared__ alignas(16) float hn[H];
    __shared__ float logits[R + 1];
    __shared__ int   act_sh;
    const int b = blockIdx.x, t = threadIdx.x;
    const int wvi = t >> 6, ln = t & 63;
    const size_t gbase = (size_t)b * H3;
    if (t < 256){
        const int g = t << 1;
        float irx=0.f, iry=0.f, izx=0.f, izy=0.f, inx=0.f, iny=0.f;
        float hrx=0.f, hry=0.f, hzx=0.f, hzy=0.f, hnx=0.f, hny=0.f;
        for (int z = 0; z < ksp; ++z){
            const float* gp = gip + (size_t)z * B * H3 + gbase;
            const float* hp = ghp + (size_t)z * B * H3 + gbase;
            float2 v;
            v = *(const float2*)(gp + g);        irx += v.x; iry += v.y;
            v = *(const float2*)(gp + H + g);    izx += v.x; izy += v.y;
            v = *(const float2*)(gp + 2*H + g);  inx += v.x; iny += v.y;
            v = *(const float2*)(hp + g);        hrx += v.x; hry += v.y;
            v = *(const float2*)(hp + H + g);    hzx += v.x; hzy += v.y;
            v = *(const float2*)(hp + 2*H + g);  hnx += v.x; hny += v.y;
        }
        const float2 hprev = *(const float2*)(hold + (size_t)b * H + g);
        const float hv0 = gru_one(irx, hrx, izx, hzx, inx, hnx, hprev.x);
        const float hv1 = gru_one(iry, hry, izy, hzy, iny, hny, hprev.y);
        hn[g] = hv0; hn[g+1] = hv1;
        float2 hw; hw.x = hv0; hw.y = hv1;
        *(float2*)(hnew_out + (size_t)b * H + g) = hw;
    }
    __syncthreads();
    {
        const float4* hn4 = (const float4*)hn;
        const float4 h0 = hn4[ln*2], h1 = hn4[ln*2+1];
        for (int i = wvi; i < R + 1; i += 8){
            const float* wr = (i < R) ? Wp + (size_t)i * H : We;
            const float4* wr4 = (const float4*)wr;
            const float4 w0 = wr4[ln*2], w1 = wr4[ln*2+1];
            float a = h0.x*w0.x + h0.y*w0.y + h0.z*w0.z + h0.w*w0.w
                    + h1.x*w1.x + h1.y*w1.y + h1.z*w1.z + h1.w*w1.w;
            a = wred_sum(a);
            if (ln == 0) logits[i] = a + (i < R ? bp[i] : be[0]);
        }
    }
    __syncthreads();
    if (wvi == 0){
        const float v = (ln < R + 1) ? logits[ln] : -INFINITY;
        const float m = wred_maxf(v);
        const float p = v - m;
        const float e = (ln < R + 1) ? expf(p) : 0.f;
        const float lse = logf(wred_sum(e));
        const float q = p - lse;
        float bv = q; int bi = ln;
        #pragma unroll
        for (int o = 32; o > 0; o >>= 1){
            float ov = __shfl_xor(bv, o);
            int   oi = __shfl_xor(bi, o);
            if (ov > bv || (ov == bv && oi < bi)){ bv = ov; bi = oi; }
        }
        if (ln < R + 1)
            out_rel[(size_t)c * B * (R+1) + (size_t)b * (R+1) + ln] = q;
        if (ln == 0){
            out_act[(size_t)(3*c) * B + b] = (float)bi;
            act_sh = bi;
        }
    }
    __syncthreads();
    {
        const float4* rg4 = (const float4*)(rel_gi_c + (size_t)act_sh * H3);
        const float4* gx4 = (const float4*)(gixc_c + gbase);
        float4* go4 = (float4*)(gi_next + gbase);
        if (t < H3/4){
            float4 a = rg4[t], bq = gx4[t];
            a.x += bq.x; a.y += bq.y; a.z += bq.z; a.w += bq.w;
            go4[t] = a;
        }
    }
}

// == fused copy step — 512 threads ==
__global__ __launch_bounds__(512) void k_copy_fused(
    const float* __restrict__ gip, const float* __restrict__ ghp,
    int gi_full, int ksp,
    const float* __restrict__ v,
    const float* __restrict__ hold,
    const float* __restrict__ W_fuse, const float* __restrict__ b_fuse,
    const float* __restrict__ W_copy, const float* __restrict__ b_copy,
    const float* __restrict__ We, const float* __restrict__ be,
    const int* __restrict__ sentence, const float* __restrict__ word_emb,
    float* __restrict__ out_copy, int slot,
    float* __restrict__ emb, float* __restrict__ out_act, int aslot,
    float* __restrict__ hnew_out, const float* __restrict__ dec, int cell_end)
{
    __shared__ alignas(16) float hn[H];
    __shared__ alignas(16) float shl[H];
    __shared__ float u_lds[100];
    __shared__ float wc_lds[100];
    __shared__ float sco[101];
    __shared__ int   act_sh;
    const int b = blockIdx.x, t = threadIdx.x;
    const int wvi = t >> 6, ln = t & 63;
    const size_t gbase = (size_t)b * H3;
    if (t < 256){
        const int g = t << 1;
        float irx, iry, izx, izy, inx, iny;
        if (gi_full){
            float2 v2;
            v2 = *(const float2*)(gip + gbase + g);        irx = v2.x; iry = v2.y;
            v2 = *(const float2*)(gip + gbase + H + g);    izx = v2.x; izy = v2.y;
            v2 = *(const float2*)(gip + gbase + 2*H + g);  inx = v2.x; iny = v2.y;
        } else {
            irx = iry = izx = izy = inx = iny = 0.f;
            for (int z = 0; z < ksp; ++z){
                const float* gp = gip + (size_t)z * B * H3 + gbase;
                float2 v2;
                v2 = *(const float2*)(gp + g);        irx += v2.x; iry += v2.y;
                v2 = *(const float2*)(gp + H + g);    izx += v2.x; izy += v2.y;
                v2 = *(const float2*)(gp + 2*H + g);  inx += v2.x; iny += v2.y;
            }
        }
        float hrx=0.f, hry=0.f, hzx=0.f, hzy=0.f, hnx=0.f, hny=0.f;
        for (int z = 0; z < ksp; ++z){
            const float* hp = ghp + (size_t)z * B * H3 + gbase;
            float2 v2;
            v2 = *(const float2*)(hp + g);        hrx += v2.x; hry += v2.y;
            v2 = *(const float2*)(hp + H + g);    hzx += v2.x; hzy += v2.y;
            v2 = *(const float2*)(hp + 2*H + g);  hnx += v2.x; hny += v2.y;
        }
        const float2 hprev = *(const float2*)(hold + (size_t)b * H + g);
        const float hv0 = gru_one(irx, hrx, izx, hzx, inx, hnx, hprev.x);
        const float hv1 = gru_one(iry, hry, izy, hzy, iny, hny, hprev.y);
        hn[g] = hv0; hn[g+1] = hv1;
        shl[g] = selu_f(hv0); shl[g+1] = selu_f(hv1);
        float2 hw;
        if (cell_end){
            const float2 d2 = *(const float2*)(dec + (size_t)b * H + g);
            hw.x = 0.5f * (d2.x + hv0); hw.y = 0.5f * (d2.y + hv1);
        } else { hw.x = hv0; hw.y = hv1; }
        *(float2*)(hnew_out + (size_t)b * H + g) = hw;
    }
    if (t >= 256 && t < 356) wc_lds[t - 256] = W_copy[t - 256];
    __syncthreads();
    {
        const float4* sh4 = (const float4*)shl;
        const float4 s0 = sh4[ln*2], s1 = sh4[ln*2+1];
        for (int n = wvi; n < 100; n += 8){
            const float4* wr4 = (const float4*)(W_fuse + (size_t)n * (2*H));
            const float4 w0 = wr4[ln*2], w1 = wr4[ln*2+1];
            float a = s0.x*w0.x + s0.y*w0.y + s0.z*w0.z + s0.w*w0.w
                    + s1.x*w1.x + s1.y*w1.y + s1.z*w1.z + s1.w*w1.w;
            a = wred_sum(a);
            if (ln == 0) u_lds[n] = a + b_fuse[n];
        }
        if (wvi == 7){
            const float4* hn4 = (const float4*)hn;
            const float4 h0 = hn4[ln*2], h1 = hn4[ln*2+1];
            const float4* we4 = (const float4*)We;
            const float4 w0 = we4[ln*2], w1 = we4[ln*2+1];
            float a = h0.x*w0.x + h0.y*w0.y + h0.z*w0.z + h0.w*w0.w
                    + h1.x*w1.x + h1.y*w1.y + h1.z*w1.z + h1.w*w1.w;
            a = wred_sum(a);
            if (ln == 0) sco[100] = a + be[0];
        }
    }
    __syncthreads();
    const float bc = b_copy[0];
    for (int s = wvi; s < S; s += 8){
        const float* vb = v + ((size_t)b * S + s) * 100;
        float a = selu_f(u_lds[ln] + vb[ln]) * wc_lds[ln];
        if (ln + 64 < 100) a += selu_f(u_lds[ln + 64] + vb[ln + 64]) * wc_lds[ln + 64];
        a = wred_sum(a);
        if (ln == 0) sco[s] = a + bc;
    }
    __syncthreads();
    if (wvi == 0){
        const float v1 = sco[ln];
        const int i2 = ln + 64;
        const float v2 = (i2 <= S) ? sco[i2] : -INFINITY;
        const float m = wred_maxf(fmaxf(v1, v2));
        const float p1 = v1 - m, p2 = v2 - m;
        float e = expf(p1) + ((i2 <= S) ? expf(p2) : 0.f);
        const float lse = logf(wred_sum(e));
        const float q1 = p1 - lse, q2 = p2 - lse;
        float bv; int bi;
        if (q2 > q1){ bv = q2; bi = i2; } else { bv = q1; bi = ln; }
        #pragma unroll
        for (int o = 32; o > 0; o >>= 1){
            float ov = __shfl_xor(bv, o);
            int   oi = __shfl_xor(bi, o);
            if (ov > bv || (ov == bv && oi < bi)){ bv = ov; bi = oi; }
        }
        const size_t obase = (size_t)slot * B * (S+1) + (size_t)b * (S+1);
        out_copy[obase + ln] = q1;
        if (i2 <= S) out_copy[obase + i2] = q2;
        if (ln == 0){
            out_act[(size_t)aslot * B + b] = (float)bi;
            act_sh = bi;
        }
    }
    __syncthreads();
    const int act = act_sh;
    const int wd = sentence[b * S + (act < S ? act : S - 1)];
    if (t < 256){
        const float2* wr2 = (const float2*)(word_emb + (size_t)wd * E);
        ((float2*)(emb + (size_t)b * E))[t] = wr2[t];
    }
}

extern "C" void kernel_launch(void* const* d_in, const int* in_sizes, int n_in,
                              void* d_out, int out_size, void* d_ws, size_t ws_size,
                              hipStream_t stream)
{
    (void)in_sizes; (void)n_in; (void)out_size;
    const int*   sentence = (const int*)  d_in[0];
    const float* dec      = (const float*)d_in[1];
    const float* enc      = (const float*)d_in[2];
    const float* word_emb = (const float*)d_in[3];
    const float* rel_emb  = (const float*)d_in[4];
    const float* sos      = (const float*)d_in[5];
    const float* W_comb   = (const float*)d_in[6];
    const float* b_comb   = (const float*)d_in[7];
    const float* W_attn   = (const float*)d_in[8];
    // d_in[9] = b_attn (cancels in softmax)
    const float* W_ih     = (const float*)d_in[10];
    const float* W_hh     = (const float*)d_in[11];
    const float* b_ih     = (const float*)d_in[12];
    const float* b_hh     = (const float*)d_in[13];
    const float* W_eos    = (const float*)d_in[14];
    const float* b_eos    = (const float*)d_in[15];
    const float* W_pred   = (const float*)d_in[16];
    const float* b_pred   = (const float*)d_in[17];
    const float* W_fuse   = (const float*)d_in[18];
    const float* b_fuse   = (const float*)d_in[19];
    const float* W_copy   = (const float*)d_in[20];
    const float* b_copy   = (const float*)d_in[21];

    float* out       = (float*)d_out;
    float* out_rel   = out;
    float* out_copy  = out + (size_t)NC * B * (R + 1);
    float* out_act   = out_copy + (size_t)2 * NC * B * (S + 1);

    float* p = (float*)d_ws;
    float* v_buf  = p; p += (size_t)B * S * 100;
    float* Wihc   = p; p += (size_t)NC * H3 * E;
    float* gixc   = p; p += (size_t)NC * B * H3;
    float* rel_gi = p; p += (size_t)NC * 64 * H3;
    float* WcT    = p; p += (size_t)(H + E) * E;
    float* relx   = p; p += (size_t)64 * E;
    float* xc     = p; p += B * E;
    float* emb    = p; p += B * E;
    float* hb0    = p; p += B * H;
    float* hb1    = p; p += B * H;
    const size_t fixed_floats = (size_t)(p - (float*)d_ws);
    int ksp = 8;
    if ((fixed_floats + (size_t)2 * 8 * B * H3) * 4 > ws_size) ksp = 4;
    float* gip = p; p += (size_t)ksp * B * H3;
    float* ghp = p; p += (size_t)ksp * B * H3;
    float* hb[2] = { hb0, hb1 };

    // ---- P0 (596 blocks, R17 layout) ----
    k_pre0<<<596, 256, 0, stream>>>(sos, dec, enc, W_attn, W_comb, b_comb, rel_emb,
                                    W_fuse, emb, hb0, WcT, xc, relx, v_buf);

    // ---- P1 mega multi-GEMM {Wihc, gixc, rel_gi}: 128x128 tiles, 420 blocks (R17) ----
    Jobs4 js;
    js.j[0] = { W_ih, E, (long long)H3 * E, H3,
                WcT, E, 0, nullptr, 0, nullptr, 0, 0,
                Wihc, E, (long long)H3 * E, E, E, 0, 4, 12, 0 };
    js.j[1] = { xc, E, 0, B,
                W_ih, E, (long long)H3 * E, b_ih, H3, nullptr, 0, 0,
                gixc, H3, (long long)B * H3, H3, E, 0, 12, 2, 240 };
    js.j[2] = { relx, E, 0, R + 1,
                W_ih, E, (long long)H3 * E, nullptr, 0, nullptr, 0, 0,
                rel_gi, H3, (long long)64 * H3, H3, E, 0, 12, 1, 360 };
    js.j[3] = js.j[2];
    js.j[3].base = 1 << 30;   // sentinel, never selected
    k_mgemm<<<420, 256, 0, stream>>>(js);

    int cur = 0;
    for (int c = 0; c < NC; ++c){
        const float* Wihc_c = Wihc + (size_t)c * H3 * E;
        const float* Whh_c  = W_hh + (size_t)c * H3 * H;
        const float* gixc_c = gixc + (size_t)c * B * H3;
        const float* bhh_c  = b_hh + (size_t)c * H3;
        for (int t3 = 0; t3 < 3; ++t3){
            const int giOn = (t3 != 1);
            if (ksp == 8){
                k_gru2_k64<<<dim3(giOn ? 24 : 12, 4, 8), 256, 0, stream>>>(
                    emb, hb[cur], Wihc_c, Whh_c, gixc_c, bhh_c,
                    gip, ghp, giOn);
            } else {
                k_gru2<<<dim3(giOn ? 24 : 12, 4, ksp), 256, 0, stream>>>(
                    emb, hb[cur], Wihc_c, Whh_c, gixc_c, bhh_c,
                    gip, ghp, giOn, ksp);
            }
            if (t3 == 0){
                k_rel_fused<<<B, 512, 0, stream>>>(
                    gip, ghp, ksp, hb[cur], W_pred, b_pred, W_eos, b_eos,
                    rel_gi + (size_t)c * 64 * H3, gixc_c, gip,
                    out_rel, c, out_act, hb[cur^1]);
            } else {
                k_copy_fused<<<B, 512, 0, stream>>>(
                    gip, ghp, (t3 == 1) ? 1 : 0, ksp, v_buf, hb[cur],
                    W_fuse, b_fuse, W_copy, b_copy, W_eos, b_eos,
                    sentence, word_emb,
                    out_copy, 2*c + (t3-1), emb, out_act, 3*c + t3,
                    hb[cur^1], dec, (t3 == 2) ? 1 : 0);
            }
            cur ^= 1;
        }
    }
}